// Round 16
// baseline (105.499 us; speedup 1.0000x reference)
//
#include <hip/hip_runtime.h>

#define D 64
#define K3 192  // 3*D
#define OUTD 64
#define KPB 512      // keys per bucket
#define KPB_LOG 9
#define NBMAX 256    // supports M <= 131072
#define ABATCH 4096  // edges per bin block (16 per thread)
#define CAP 8192     // staged/e_pack capacity per bucket (mean 4096, sigma 64)

typedef __attribute__((ext_vector_type(8))) short bf16x8;
typedef __attribute__((ext_vector_type(4))) float f32x4;

static __device__ __forceinline__ unsigned short f2bf(float f) {
    unsigned u = __float_as_uint(f);
    u += 0x7fffu + ((u >> 16) & 1u);  // round-to-nearest-even
    return (unsigned short)(u >> 16);
}
static __device__ __forceinline__ float bf2f(unsigned short h) {
    return __uint_as_float((unsigned)h << 16);
}

// ---------------------------------------------------------------------------
// Pass 0 (one-time): bake coef-scaled W_fc into MFMA B-fragment layout (bf16),
// convert feat -> bf16, init per-bucket staging cursors. No memsets anywhere.
// ---------------------------------------------------------------------------
__global__ __launch_bounds__(256) void prep_kernel(
        const float* __restrict__ W_fc,
        const float* __restrict__ coef_self,
        const float* __restrict__ coef_posi,
        const float* __restrict__ coef_nega,
        const float* __restrict__ feat,
        unsigned short* __restrict__ Bfrag,
        unsigned short* __restrict__ feat16,
        int* __restrict__ cursorA, int NB, int ND4) {
    int i = blockIdx.x * blockDim.x + threadIdx.x;
    if (i < NB) cursorA[i] = i * CAP;
    if (i < 6 * 4 * 64 * 8) {
        int j    = i & 7;
        int lane = (i >> 3) & 63;
        int nt   = (i >> 9) & 3;
        int kt   = i >> 11;
        int n = nt * 16 + (lane & 15);
        int k = kt * 32 + (lane >> 4) * 8 + j;
        float cf = (k < 64) ? coef_self[0] : (k < 128 ? coef_posi[0] : coef_nega[0]);
        Bfrag[i] = f2bf(W_fc[n * K3 + k] * cf);
    }
    if (i < ND4) {  // 4 feats per thread
        float4 v = *(const float4*)&feat[(size_t)i * 4];
        unsigned long long p =
            (unsigned long long)f2bf(v.x) |
            ((unsigned long long)f2bf(v.y) << 16) |
            ((unsigned long long)f2bf(v.z) << 32) |
            ((unsigned long long)f2bf(v.w) << 48);
        *(unsigned long long*)&feat16[(size_t)i * 4] = p;
    }
}

// ---------------------------------------------------------------------------
// Pass A: bin edges into fixed-capacity bucket staging.
// bucket = key >> 9, key = 2*dst + (w<0).
// Record: x = w bits, y = (src << 9) | (key & 511).
// ---------------------------------------------------------------------------
__global__ __launch_bounds__(256) void bin_kernel(
        const float* __restrict__ w, const int* __restrict__ src,
        const int* __restrict__ dst, int* __restrict__ cursorA,
        uint2* __restrict__ staged, int E, int NB) {
    __shared__ int cnt[NBMAX];
    __shared__ int base[NBMAX];
    int t = threadIdx.x;
    int e0 = blockIdx.x * ABATCH;
    for (int i = t; i < NB; i += 256) cnt[i] = 0;
    __syncthreads();

    unsigned wv[16], yv[16];
    int bk[16], rk[16];
#pragma unroll
    for (int j = 0; j < 16; ++j) {
        int e = e0 + j * 256 + t;  // coalesced per round
        if (e < E) {
            float we = w[e];
            int key = 2 * dst[e] + (we < 0.0f ? 1 : 0);
            wv[j] = __float_as_uint(we);
            yv[j] = ((unsigned)src[e] << KPB_LOG) | (unsigned)(key & (KPB - 1));
            bk[j] = key >> KPB_LOG;
            rk[j] = atomicAdd(&cnt[bk[j]], 1);
        } else {
            bk[j] = -1;
        }
    }
    __syncthreads();
    for (int b = t; b < NB; b += 256) {
        int c = cnt[b];
        if (c > 0) base[b] = atomicAdd(&cursorA[b], c);
    }
    __syncthreads();
#pragma unroll
    for (int j = 0; j < 16; ++j) {
        if (bk[j] >= 0) {
            int pos = base[bk[j]] + rk[j];
            if (pos < (bk[j] + 1) * CAP)  // defensive (60-sigma event)
                staged[pos] = make_uint2(wv[j], yv[j]);
        }
    }
}

// ---------------------------------------------------------------------------
// Pass B: per-bucket fused key-hist + scan + scatter. One block per bucket.
// ---------------------------------------------------------------------------
__global__ __launch_bounds__(256) void bucket_scatter_kernel(
        const int* __restrict__ cursorA, const uint2* __restrict__ staged,
        int2* __restrict__ seg_be, uint2* __restrict__ e_pack, int M) {
    __shared__ int cnt[KPB];   // counts, then cursors
    __shared__ int wt[4];
    int b = blockIdx.x;
    int t = threadIdx.x;
    int lane = t & 63;
    int wid = t >> 6;
    int kb = b << KPB_LOG;
    int nk = min(KPB, M - kb);
    int beg = b * CAP;
    int end = min(cursorA[b], beg + CAP);  // cursor = base + count

    cnt[2 * t] = 0;
    cnt[2 * t + 1] = 0;
    __syncthreads();
    for (int i = beg + t; i < end; i += 256)
        atomicAdd(&cnt[staged[i].y & (KPB - 1)], 1);
    __syncthreads();

    // block exclusive scan of 512 counts (2 per thread)
    int v0 = cnt[2 * t], v1 = cnt[2 * t + 1];
    int ps = v0 + v1;
    int incl = ps;
#pragma unroll
    for (int o = 1; o < 64; o <<= 1) {
        int u = __shfl_up(incl, o);
        if (lane >= o) incl += u;
    }
    if (lane == 63) wt[wid] = incl;
    __syncthreads();
    int wb = 0;
    for (int j = 0; j < wid; ++j) wb += wt[j];
    int excl = wb + (incl - ps);

    int p0 = beg + excl;
    int p1 = p0 + v0;
    if (2 * t < nk) seg_be[kb + 2 * t] = make_int2(p0, p1);
    if (2 * t + 1 < nk) seg_be[kb + 2 * t + 1] = make_int2(p1, p1 + v1);
    __syncthreads();
    cnt[2 * t] = p0;      // reuse as cursors
    cnt[2 * t + 1] = p1;
    __syncthreads();

    for (int i = beg + t; i < end; i += 256) {
        uint2 r = staged[i];
        int kl = (int)(r.y & (KPB - 1));
        int p = atomicAdd(&cnt[kl], 1);
        e_pack[p] = make_uint2(r.x, r.y >> KPB_LOG);
    }
}

// ---------------------------------------------------------------------------
// Pass 4: aggregation. ONE WAVE PER (node,sign) BIN.
// Metadata prefetched LANE-PARALLEL (one coalesced uint2 vload covers 64
// edges), then per-edge broadcast via v_readlane (no memory latency in the
// chain) -> all gathers of a seg issue back-to-back. Sign-split bins: no
// max-subtraction needed (softmax shift-invariance, |w| < ~6 safe in f32).
// ---------------------------------------------------------------------------
__global__ __launch_bounds__(256) void node_agg_kernel(
        const unsigned short* __restrict__ feat16,
        const int2* __restrict__ seg_be,  // len 2N
        const uint2* __restrict__ e_pack,
        unsigned short* __restrict__ h_pos,
        unsigned short* __restrict__ h_neg, int N) {
    int lane = threadIdx.x & 63;
    int seg = (blockIdx.x * blockDim.x + threadIdx.x) >> 6;
    if (seg >= 2 * N) return;
    int2 be = seg_be[seg];
    int beg = __builtin_amdgcn_readfirstlane(be.x);
    int end = __builtin_amdgcn_readfirstlane(be.y);
    int isneg = seg & 1;

    float s = 0.0f, acc = 0.0f;
    for (int base = beg; base < end; base += 64) {
        int e = min(base + lane, end - 1);
        uint2 pk = e_pack[e];             // lane-parallel metadata prefetch
        int cnt = min(64, end - base);
        if (isneg) {
            for (int j = 0; j < cnt; ++j) {
                float wj = __uint_as_float(
                    __builtin_amdgcn_readlane((int)pk.x, j));
                int sj = __builtin_amdgcn_readlane((int)pk.y, j);
                float aj = __expf(-wj);                 // wj < 0
                s += aj;
                acc = fmaf(bf2f(feat16[(size_t)sj * D + lane]), aj, acc);
            }
        } else {
            for (int j = 0; j < cnt; ++j) {
                float wj = __uint_as_float(
                    __builtin_amdgcn_readlane((int)pk.x, j));
                int sj = __builtin_amdgcn_readlane((int)pk.y, j);
                float aj = (wj > 0.0f) ? __expf(wj) : 0.0f;  // exclude w==0
                s += aj;
                acc = fmaf(bf2f(feat16[(size_t)sj * D + lane]), aj, acc);
            }
        }
    }
    float r = acc / (s + 1e-16f);
    unsigned short* h = isneg ? h_neg : h_pos;
    h[(size_t)(seg >> 1) * D + lane] = f2bf(r);
}

// ---------------------------------------------------------------------------
// Pass 5: output projection via MFMA. One wave per 16 nodes.
// A-operands are DIRECT bf16x8 loads (coef folded into Bfrag at prep).
// ---------------------------------------------------------------------------
__global__ __launch_bounds__(256) void out_gemm_mfma(
        const unsigned short* __restrict__ feat16,
        const unsigned short* __restrict__ h_pos,
        const unsigned short* __restrict__ h_neg,
        const unsigned short* __restrict__ Bfrag,
        const float* __restrict__ b_fc,
        const float* __restrict__ bias,
        float* __restrict__ out,
        int N) {
    int lane = threadIdx.x & 63;
    int wv = (blockIdx.x * blockDim.x + threadIdx.x) >> 6;
    int node0 = wv * 16;
    if (node0 >= N) return;

    const bf16x8* bp = (const bf16x8*)Bfrag;
    bf16x8 bfr[24];
#pragma unroll
    for (int f = 0; f < 24; ++f) bfr[f] = bp[f * 64 + lane];

    const unsigned short* segs[3];
    segs[0] = feat16;
    segs[1] = h_pos;
    segs[2] = h_neg;

    int m = lane & 15;          // A row / D col
    int kg = lane >> 4;         // k-group
    int node = node0 + m;
    bool mvalid = node < N;

    f32x4 acc[4];
#pragma unroll
    for (int nt = 0; nt < 4; ++nt) acc[nt] = (f32x4){0.f, 0.f, 0.f, 0.f};

#pragma unroll
    for (int kt = 0; kt < 6; ++kt) {
        int sg = kt >> 1;
        bf16x8 a;
        if (mvalid) {
            a = *(const bf16x8*)(segs[sg] + (size_t)node * D + (kt & 1) * 32 + kg * 8);
        } else {
            a = (bf16x8){0, 0, 0, 0, 0, 0, 0, 0};
        }
#pragma unroll
        for (int nt = 0; nt < 4; ++nt)
            acc[nt] = __builtin_amdgcn_mfma_f32_16x16x32_bf16(
                a, bfr[kt * 4 + nt], acc[nt], 0, 0, 0);
    }

#pragma unroll
    for (int nt = 0; nt < 4; ++nt) {
        int col = nt * 16 + m;
        float bb = b_fc[col] + bias[col];
#pragma unroll
        for (int j = 0; j < 4; ++j) {
            int row = node0 + 4 * kg + j;
            if (row < N) out[(size_t)row * OUTD + col] = acc[nt][j] + bb;
        }
    }
}

extern "C" void kernel_launch(void* const* d_in, const int* in_sizes, int n_in,
                              void* d_out, int out_size, void* d_ws, size_t ws_size,
                              hipStream_t stream) {
    const float* feat      = (const float*)d_in[0];
    const float* w         = (const float*)d_in[1];
    const float* W_fc      = (const float*)d_in[2];
    const float* b_fc      = (const float*)d_in[3];
    const float* bias      = (const float*)d_in[4];
    const float* coef_self = (const float*)d_in[5];
    const float* coef_posi = (const float*)d_in[6];
    const float* coef_nega = (const float*)d_in[7];
    const int*   src       = (const int*)d_in[8];
    const int*   dst       = (const int*)d_in[9];

    const int E = in_sizes[1];
    const int N = in_sizes[0] / D;
    const int M = 2 * N;                      // sign-split bins
    const int NB = (M + KPB - 1) / KPB;       // 196 buckets (<=256 req.)

    // Workspace layout:
    //   seg_be [M]x8B | cursorA [NB]x4 | Bfrag [12288 u16] | feat16 [N*D u16]
    //   | e_pack [NB*CAP]x8B | staged [NB*CAP]x8B | h_pos [N*D u16] | h_neg [N*D u16]
    char* ws = (char*)d_ws;
    int2*  seg_be   = (int2*)ws;
    int*   cursorA  = (int*)(ws + (size_t)M * 8);
    size_t bfrag_off = (((size_t)M * 8 + (size_t)NB * 4) + 15) & ~(size_t)15;
    unsigned short* Bfrag = (unsigned short*)(ws + bfrag_off);
    size_t feat16_off = bfrag_off + 6 * 4 * 64 * 8 * 2;
    unsigned short* feat16 = (unsigned short*)(ws + feat16_off);
    size_t epack_off = (feat16_off + (size_t)N * D * 2 + 7) & ~(size_t)7;
    uint2* e_pack  = (uint2*)(ws + epack_off);
    uint2* staged  = e_pack + (size_t)NB * CAP;
    unsigned short* h_pos = (unsigned short*)((char*)(staged + (size_t)NB * CAP));
    unsigned short* h_neg = h_pos + (size_t)N * D;

    const int ND4 = N * D / 4;
    int pb = (max(ND4, 6 * 4 * 64 * 8) + 255) / 256;
    prep_kernel<<<pb, 256, 0, stream>>>(W_fc, coef_self, coef_posi, coef_nega,
                                        feat, Bfrag, feat16, cursorA, NB, ND4);
    bin_kernel<<<(E + ABATCH - 1) / ABATCH, 256, 0, stream>>>(
        w, src, dst, cursorA, staged, E, NB);
    bucket_scatter_kernel<<<NB, 256, 0, stream>>>(cursorA, staged, seg_be,
                                                  e_pack, M);

    int segb = (M * 64 + 255) / 256;
    node_agg_kernel<<<segb, 256, 0, stream>>>(feat16, seg_be, e_pack,
                                              h_pos, h_neg, N);

    int nwaves = (N + 15) / 16;
    int gb = (nwaves + 3) / 4;  // 4 waves per 256-thread block
    out_gemm_mfma<<<gb, 256, 0, stream>>>(feat16, h_pos, h_neg, Bfrag,
                                          b_fc, bias, (float*)d_out, N);
}

// Round 17
// 86.904 us; speedup vs baseline: 1.2140x; 1.2140x over previous
//
#include <hip/hip_runtime.h>

#define D 64
#define K3 192  // 3*D
#define OUTD 64
#define KPB 512      // keys per bucket
#define KPB_LOG 9
#define NBMAX 256    // supports M <= 131072
#define ABATCH 4096  // edges per bin block (16 per thread)
#define CAP 8192     // staged/e_pack capacity per bucket (mean 4096, sigma 64)

typedef __attribute__((ext_vector_type(8))) short bf16x8;
typedef __attribute__((ext_vector_type(4))) float f32x4;

static __device__ __forceinline__ unsigned short f2bf(float f) {
    unsigned u = __float_as_uint(f);
    u += 0x7fffu + ((u >> 16) & 1u);  // round-to-nearest-even
    return (unsigned short)(u >> 16);
}
static __device__ __forceinline__ float bf2f(unsigned short h) {
    return __uint_as_float((unsigned)h << 16);
}

// ---------------------------------------------------------------------------
// Pass 0 (one-time): bake coef-scaled W_fc into MFMA B-fragment layout (bf16),
// convert feat -> bf16, init per-bucket staging cursors. No memsets anywhere.
// ---------------------------------------------------------------------------
__global__ __launch_bounds__(256) void prep_kernel(
        const float* __restrict__ W_fc,
        const float* __restrict__ coef_self,
        const float* __restrict__ coef_posi,
        const float* __restrict__ coef_nega,
        const float* __restrict__ feat,
        unsigned short* __restrict__ Bfrag,
        unsigned short* __restrict__ feat16,
        int* __restrict__ cursorA, int NB, int ND4) {
    int i = blockIdx.x * blockDim.x + threadIdx.x;
    if (i < NB) cursorA[i] = i * CAP;
    if (i < 6 * 4 * 64 * 8) {
        int j    = i & 7;
        int lane = (i >> 3) & 63;
        int nt   = (i >> 9) & 3;
        int kt   = i >> 11;
        int n = nt * 16 + (lane & 15);
        int k = kt * 32 + (lane >> 4) * 8 + j;
        float cf = (k < 64) ? coef_self[0] : (k < 128 ? coef_posi[0] : coef_nega[0]);
        Bfrag[i] = f2bf(W_fc[n * K3 + k] * cf);
    }
    if (i < ND4) {  // 4 feats per thread
        float4 v = *(const float4*)&feat[(size_t)i * 4];
        unsigned long long p =
            (unsigned long long)f2bf(v.x) |
            ((unsigned long long)f2bf(v.y) << 16) |
            ((unsigned long long)f2bf(v.z) << 32) |
            ((unsigned long long)f2bf(v.w) << 48);
        *(unsigned long long*)&feat16[(size_t)i * 4] = p;
    }
}

// ---------------------------------------------------------------------------
// Pass A: bin edges into fixed-capacity bucket staging.
// bucket = key >> 9, key = 2*dst + (w<0).
// Record: x = w bits, y = (src << 9) | (key & 511).
// ---------------------------------------------------------------------------
__global__ __launch_bounds__(256) void bin_kernel(
        const float* __restrict__ w, const int* __restrict__ src,
        const int* __restrict__ dst, int* __restrict__ cursorA,
        uint2* __restrict__ staged, int E, int NB) {
    __shared__ int cnt[NBMAX];
    __shared__ int base[NBMAX];
    int t = threadIdx.x;
    int e0 = blockIdx.x * ABATCH;
    for (int i = t; i < NB; i += 256) cnt[i] = 0;
    __syncthreads();

    unsigned wv[16], yv[16];
    int bk[16], rk[16];
#pragma unroll
    for (int j = 0; j < 16; ++j) {
        int e = e0 + j * 256 + t;  // coalesced per round
        if (e < E) {
            float we = w[e];
            int key = 2 * dst[e] + (we < 0.0f ? 1 : 0);
            wv[j] = __float_as_uint(we);
            yv[j] = ((unsigned)src[e] << KPB_LOG) | (unsigned)(key & (KPB - 1));
            bk[j] = key >> KPB_LOG;
            rk[j] = atomicAdd(&cnt[bk[j]], 1);
        } else {
            bk[j] = -1;
        }
    }
    __syncthreads();
    for (int b = t; b < NB; b += 256) {
        int c = cnt[b];
        if (c > 0) base[b] = atomicAdd(&cursorA[b], c);
    }
    __syncthreads();
#pragma unroll
    for (int j = 0; j < 16; ++j) {
        if (bk[j] >= 0) {
            int pos = base[bk[j]] + rk[j];
            if (pos < (bk[j] + 1) * CAP)  // defensive (60-sigma event)
                staged[pos] = make_uint2(wv[j], yv[j]);
        }
    }
}

// ---------------------------------------------------------------------------
// Pass B: per-bucket fused key-hist + scan + scatter. One block per bucket.
// ---------------------------------------------------------------------------
__global__ __launch_bounds__(256) void bucket_scatter_kernel(
        const int* __restrict__ cursorA, const uint2* __restrict__ staged,
        int2* __restrict__ seg_be, uint2* __restrict__ e_pack, int M) {
    __shared__ int cnt[KPB];   // counts, then cursors
    __shared__ int wt[4];
    int b = blockIdx.x;
    int t = threadIdx.x;
    int lane = t & 63;
    int wid = t >> 6;
    int kb = b << KPB_LOG;
    int nk = min(KPB, M - kb);
    int beg = b * CAP;
    int end = min(cursorA[b], beg + CAP);  // cursor = base + count

    cnt[2 * t] = 0;
    cnt[2 * t + 1] = 0;
    __syncthreads();
    for (int i = beg + t; i < end; i += 256)
        atomicAdd(&cnt[staged[i].y & (KPB - 1)], 1);
    __syncthreads();

    // block exclusive scan of 512 counts (2 per thread)
    int v0 = cnt[2 * t], v1 = cnt[2 * t + 1];
    int ps = v0 + v1;
    int incl = ps;
#pragma unroll
    for (int o = 1; o < 64; o <<= 1) {
        int u = __shfl_up(incl, o);
        if (lane >= o) incl += u;
    }
    if (lane == 63) wt[wid] = incl;
    __syncthreads();
    int wb = 0;
    for (int j = 0; j < wid; ++j) wb += wt[j];
    int excl = wb + (incl - ps);

    int p0 = beg + excl;
    int p1 = p0 + v0;
    if (2 * t < nk) seg_be[kb + 2 * t] = make_int2(p0, p1);
    if (2 * t + 1 < nk) seg_be[kb + 2 * t + 1] = make_int2(p1, p1 + v1);
    __syncthreads();
    cnt[2 * t] = p0;      // reuse as cursors
    cnt[2 * t + 1] = p1;
    __syncthreads();

    for (int i = beg + t; i < end; i += 256) {
        uint2 r = staged[i];
        int kl = (int)(r.y & (KPB - 1));
        int p = atomicAdd(&cnt[kl], 1);
        e_pack[p] = make_uint2(r.x, r.y >> KPB_LOG);
    }
}

// ---------------------------------------------------------------------------
// Pass 4: aggregation. ONE WAVE PER (node,sign) BIN, PAIRED EDGES.
// Half-wave 0 = even edges, half-wave 1 = odd edges; each lane loads u32
// (2 bf16 features, 4B/lane) so one wave-load covers 2 edges. Metadata via
// wave-uniform s_loads + per-half cndmask (SMEM pipe runs ahead). Body is a
// predicated straight-line of 4 pair-slots (8 edges = mean seg size): 4
// independent gathers in flight, 2 independent fmac chains. Final combine
// via shfl_xor(32); packed u32 store from 32 lanes. Sign-split bins: no
// max-subtraction needed (softmax shift-invariance, |w| < ~6 safe in f32).
// ---------------------------------------------------------------------------
__global__ __launch_bounds__(256) void node_agg_kernel(
        const unsigned short* __restrict__ feat16,
        const int2* __restrict__ seg_be,  // len 2N
        const uint2* __restrict__ e_pack,
        unsigned short* __restrict__ h_pos,
        unsigned short* __restrict__ h_neg, int N) {
    int lane = threadIdx.x & 63;
    int seg = (blockIdx.x * blockDim.x + threadIdx.x) >> 6;
    if (seg >= 2 * N) return;
    int2 be = seg_be[seg];
    int beg = __builtin_amdgcn_readfirstlane(be.x);
    int end = __builtin_amdgcn_readfirstlane(be.y);
    int isneg = seg & 1;
    int half = lane >> 5;        // 0: even edge of pair, 1: odd edge
    int fl = lane & 31;          // feature pair (features 2fl, 2fl+1)

    float s = 0.0f, acc0 = 0.0f, acc1 = 0.0f;
    for (int e = beg; e < end; e += 8) {
#pragma unroll
        for (int p = 0; p < 4; ++p) {
            int ee = e + 2 * p;                      // wave-uniform
            int eE = (ee < end) ? ee : end - 1;      // uniform clamps -> s_load
            int eO = (ee + 1 < end) ? ee + 1 : end - 1;
            uint2 pkE = e_pack[eE];
            uint2 pkO = e_pack[eO];
            unsigned wb = half ? pkO.x : pkE.x;
            int sj = (int)(half ? pkO.y : pkE.y);
            bool valid = (ee + half) < end;
            float wj = __uint_as_float(wb);
            float aj;
            if (isneg) aj = __expf(-wj);                     // wj < 0
            else       aj = (wj > 0.0f) ? __expf(wj) : 0.0f; // exclude w==0
            aj = valid ? aj : 0.0f;
            s += aj;
            unsigned fv = *(const unsigned*)(feat16 + (size_t)sj * D + 2 * fl);
            acc0 = fmaf(__uint_as_float(fv << 16), aj, acc0);          // feature 2fl
            acc1 = fmaf(__uint_as_float(fv & 0xffff0000u), aj, acc1);  // feature 2fl+1
        }
    }
    // combine halves (even-edge partials + odd-edge partials)
    s    += __shfl_xor(s, 32);
    acc0 += __shfl_xor(acc0, 32);
    acc1 += __shfl_xor(acc1, 32);
    if (half == 0) {
        float rinv = 1.0f / (s + 1e-16f);
        unsigned pck = (unsigned)f2bf(acc0 * rinv) |
                       ((unsigned)f2bf(acc1 * rinv) << 16);
        unsigned short* h = isneg ? h_neg : h_pos;
        *(unsigned*)(h + (size_t)(seg >> 1) * D + 2 * fl) = pck;
    }
}

// ---------------------------------------------------------------------------
// Pass 5: output projection via MFMA. One wave per 16 nodes.
// A-operands are DIRECT bf16x8 loads (coef folded into Bfrag at prep).
// ---------------------------------------------------------------------------
__global__ __launch_bounds__(256) void out_gemm_mfma(
        const unsigned short* __restrict__ feat16,
        const unsigned short* __restrict__ h_pos,
        const unsigned short* __restrict__ h_neg,
        const unsigned short* __restrict__ Bfrag,
        const float* __restrict__ b_fc,
        const float* __restrict__ bias,
        float* __restrict__ out,
        int N) {
    int lane = threadIdx.x & 63;
    int wv = (blockIdx.x * blockDim.x + threadIdx.x) >> 6;
    int node0 = wv * 16;
    if (node0 >= N) return;

    const bf16x8* bp = (const bf16x8*)Bfrag;
    bf16x8 bfr[24];
#pragma unroll
    for (int f = 0; f < 24; ++f) bfr[f] = bp[f * 64 + lane];

    const unsigned short* segs[3];
    segs[0] = feat16;
    segs[1] = h_pos;
    segs[2] = h_neg;

    int m = lane & 15;          // A row / D col
    int kg = lane >> 4;         // k-group
    int node = node0 + m;
    bool mvalid = node < N;

    f32x4 acc[4];
#pragma unroll
    for (int nt = 0; nt < 4; ++nt) acc[nt] = (f32x4){0.f, 0.f, 0.f, 0.f};

#pragma unroll
    for (int kt = 0; kt < 6; ++kt) {
        int sg = kt >> 1;
        bf16x8 a;
        if (mvalid) {
            a = *(const bf16x8*)(segs[sg] + (size_t)node * D + (kt & 1) * 32 + kg * 8);
        } else {
            a = (bf16x8){0, 0, 0, 0, 0, 0, 0, 0};
        }
#pragma unroll
        for (int nt = 0; nt < 4; ++nt)
            acc[nt] = __builtin_amdgcn_mfma_f32_16x16x32_bf16(
                a, bfr[kt * 4 + nt], acc[nt], 0, 0, 0);
    }

#pragma unroll
    for (int nt = 0; nt < 4; ++nt) {
        int col = nt * 16 + m;
        float bb = b_fc[col] + bias[col];
#pragma unroll
        for (int j = 0; j < 4; ++j) {
            int row = node0 + 4 * kg + j;
            if (row < N) out[(size_t)row * OUTD + col] = acc[nt][j] + bb;
        }
    }
}

extern "C" void kernel_launch(void* const* d_in, const int* in_sizes, int n_in,
                              void* d_out, int out_size, void* d_ws, size_t ws_size,
                              hipStream_t stream) {
    const float* feat      = (const float*)d_in[0];
    const float* w         = (const float*)d_in[1];
    const float* W_fc      = (const float*)d_in[2];
    const float* b_fc      = (const float*)d_in[3];
    const float* bias      = (const float*)d_in[4];
    const float* coef_self = (const float*)d_in[5];
    const float* coef_posi = (const float*)d_in[6];
    const float* coef_nega = (const float*)d_in[7];
    const int*   src       = (const int*)d_in[8];
    const int*   dst       = (const int*)d_in[9];

    const int E = in_sizes[1];
    const int N = in_sizes[0] / D;
    const int M = 2 * N;                      // sign-split bins
    const int NB = (M + KPB - 1) / KPB;       // 196 buckets (<=256 req.)

    // Workspace layout:
    //   seg_be [M]x8B | cursorA [NB]x4 | Bfrag [12288 u16] | feat16 [N*D u16]
    //   | e_pack [NB*CAP]x8B | staged [NB*CAP]x8B | h_pos [N*D u16] | h_neg [N*D u16]
    char* ws = (char*)d_ws;
    int2*  seg_be   = (int2*)ws;
    int*   cursorA  = (int*)(ws + (size_t)M * 8);
    size_t bfrag_off = (((size_t)M * 8 + (size_t)NB * 4) + 15) & ~(size_t)15;
    unsigned short* Bfrag = (unsigned short*)(ws + bfrag_off);
    size_t feat16_off = bfrag_off + 6 * 4 * 64 * 8 * 2;
    unsigned short* feat16 = (unsigned short*)(ws + feat16_off);
    size_t epack_off = (feat16_off + (size_t)N * D * 2 + 7) & ~(size_t)7;
    uint2* e_pack  = (uint2*)(ws + epack_off);
    uint2* staged  = e_pack + (size_t)NB * CAP;
    unsigned short* h_pos = (unsigned short*)((char*)(staged + (size_t)NB * CAP));
    unsigned short* h_neg = h_pos + (size_t)N * D;

    const int ND4 = N * D / 4;
    int pb = (max(ND4, 6 * 4 * 64 * 8) + 255) / 256;
    prep_kernel<<<pb, 256, 0, stream>>>(W_fc, coef_self, coef_posi, coef_nega,
                                        feat, Bfrag, feat16, cursorA, NB, ND4);
    bin_kernel<<<(E + ABATCH - 1) / ABATCH, 256, 0, stream>>>(
        w, src, dst, cursorA, staged, E, NB);
    bucket_scatter_kernel<<<NB, 256, 0, stream>>>(cursorA, staged, seg_be,
                                                  e_pack, M);

    int segb = (M * 64 + 255) / 256;
    node_agg_kernel<<<segb, 256, 0, stream>>>(feat16, seg_be, e_pack,
                                              h_pos, h_neg, N);

    int nwaves = (N + 15) / 16;
    int gb = (nwaves + 3) / 4;  // 4 waves per 256-thread block
    out_gemm_mfma<<<gb, 256, 0, stream>>>(feat16, h_pos, h_neg, Bfrag,
                                          b_fc, bias, (float*)d_out, N);
}

// Round 18
// 77.864 us; speedup vs baseline: 1.3549x; 1.1161x over previous
//
#include <hip/hip_runtime.h>

#define D 64
#define K3 192  // 3*D
#define OUTD 64
#define KPB 512      // keys per bucket
#define KPB_LOG 9
#define NBMAX 256    // supports M <= 131072
#define ABATCH 4096  // edges per bin block (16 per thread)
#define CAP 8192     // staged/e_pack capacity per bucket (mean 4096, sigma 64)

typedef __attribute__((ext_vector_type(8))) short bf16x8;
typedef __attribute__((ext_vector_type(4))) float f32x4;

static __device__ __forceinline__ unsigned short f2bf(float f) {
    unsigned u = __float_as_uint(f);
    u += 0x7fffu + ((u >> 16) & 1u);  // round-to-nearest-even
    return (unsigned short)(u >> 16);
}
static __device__ __forceinline__ float bf2f(unsigned short h) {
    return __uint_as_float((unsigned)h << 16);
}

// ---------------------------------------------------------------------------
// Pass 0 (one-time): bake coef-scaled W_fc into MFMA B-fragment layout (bf16),
// convert feat -> bf16, init per-bucket staging cursors. No memsets anywhere.
// ---------------------------------------------------------------------------
__global__ __launch_bounds__(256) void prep_kernel(
        const float* __restrict__ W_fc,
        const float* __restrict__ coef_self,
        const float* __restrict__ coef_posi,
        const float* __restrict__ coef_nega,
        const float* __restrict__ feat,
        unsigned short* __restrict__ Bfrag,
        unsigned short* __restrict__ feat16,
        int* __restrict__ cursorA, int NB, int ND4) {
    int i = blockIdx.x * blockDim.x + threadIdx.x;
    if (i < NB) cursorA[i] = i * CAP;
    if (i < 6 * 4 * 64 * 8) {
        int j    = i & 7;
        int lane = (i >> 3) & 63;
        int nt   = (i >> 9) & 3;
        int kt   = i >> 11;
        int n = nt * 16 + (lane & 15);
        int k = kt * 32 + (lane >> 4) * 8 + j;
        float cf = (k < 64) ? coef_self[0] : (k < 128 ? coef_posi[0] : coef_nega[0]);
        Bfrag[i] = f2bf(W_fc[n * K3 + k] * cf);
    }
    if (i < ND4) {  // 4 feats per thread
        float4 v = *(const float4*)&feat[(size_t)i * 4];
        unsigned long long p =
            (unsigned long long)f2bf(v.x) |
            ((unsigned long long)f2bf(v.y) << 16) |
            ((unsigned long long)f2bf(v.z) << 32) |
            ((unsigned long long)f2bf(v.w) << 48);
        *(unsigned long long*)&feat16[(size_t)i * 4] = p;
    }
}

// ---------------------------------------------------------------------------
// Pass A: bin edges into fixed-capacity bucket staging.
// bucket = key >> 9, key = 2*dst + (w<0).
// Record: x = w bits, y = (src << 9) | (key & 511).
// ---------------------------------------------------------------------------
__global__ __launch_bounds__(256) void bin_kernel(
        const float* __restrict__ w, const int* __restrict__ src,
        const int* __restrict__ dst, int* __restrict__ cursorA,
        uint2* __restrict__ staged, int E, int NB) {
    __shared__ int cnt[NBMAX];
    __shared__ int base[NBMAX];
    int t = threadIdx.x;
    int e0 = blockIdx.x * ABATCH;
    for (int i = t; i < NB; i += 256) cnt[i] = 0;
    __syncthreads();

    unsigned wv[16], yv[16];
    int bk[16], rk[16];
#pragma unroll
    for (int j = 0; j < 16; ++j) {
        int e = e0 + j * 256 + t;  // coalesced per round
        if (e < E) {
            float we = w[e];
            int key = 2 * dst[e] + (we < 0.0f ? 1 : 0);
            wv[j] = __float_as_uint(we);
            yv[j] = ((unsigned)src[e] << KPB_LOG) | (unsigned)(key & (KPB - 1));
            bk[j] = key >> KPB_LOG;
            rk[j] = atomicAdd(&cnt[bk[j]], 1);
        } else {
            bk[j] = -1;
        }
    }
    __syncthreads();
    for (int b = t; b < NB; b += 256) {
        int c = cnt[b];
        if (c > 0) base[b] = atomicAdd(&cursorA[b], c);
    }
    __syncthreads();
#pragma unroll
    for (int j = 0; j < 16; ++j) {
        if (bk[j] >= 0) {
            int pos = base[bk[j]] + rk[j];
            if (pos < (bk[j] + 1) * CAP)  // defensive (60-sigma event)
                staged[pos] = make_uint2(wv[j], yv[j]);
        }
    }
}

// ---------------------------------------------------------------------------
// Pass B: per-bucket fused key-hist + scan + scatter. One block per bucket.
// ---------------------------------------------------------------------------
__global__ __launch_bounds__(256) void bucket_scatter_kernel(
        const int* __restrict__ cursorA, const uint2* __restrict__ staged,
        int2* __restrict__ seg_be, uint2* __restrict__ e_pack, int M) {
    __shared__ int cnt[KPB];   // counts, then cursors
    __shared__ int wt[4];
    int b = blockIdx.x;
    int t = threadIdx.x;
    int lane = t & 63;
    int wid = t >> 6;
    int kb = b << KPB_LOG;
    int nk = min(KPB, M - kb);
    int beg = b * CAP;
    int end = min(cursorA[b], beg + CAP);  // cursor = base + count

    cnt[2 * t] = 0;
    cnt[2 * t + 1] = 0;
    __syncthreads();
    for (int i = beg + t; i < end; i += 256)
        atomicAdd(&cnt[staged[i].y & (KPB - 1)], 1);
    __syncthreads();

    // block exclusive scan of 512 counts (2 per thread)
    int v0 = cnt[2 * t], v1 = cnt[2 * t + 1];
    int ps = v0 + v1;
    int incl = ps;
#pragma unroll
    for (int o = 1; o < 64; o <<= 1) {
        int u = __shfl_up(incl, o);
        if (lane >= o) incl += u;
    }
    if (lane == 63) wt[wid] = incl;
    __syncthreads();
    int wb = 0;
    for (int j = 0; j < wid; ++j) wb += wt[j];
    int excl = wb + (incl - ps);

    int p0 = beg + excl;
    int p1 = p0 + v0;
    if (2 * t < nk) seg_be[kb + 2 * t] = make_int2(p0, p1);
    if (2 * t + 1 < nk) seg_be[kb + 2 * t + 1] = make_int2(p1, p1 + v1);
    __syncthreads();
    cnt[2 * t] = p0;      // reuse as cursors
    cnt[2 * t + 1] = p1;
    __syncthreads();

    for (int i = beg + t; i < end; i += 256) {
        uint2 r = staged[i];
        int kl = (int)(r.y & (KPB - 1));
        int p = atomicAdd(&cnt[kl], 1);
        e_pack[p] = make_uint2(r.x, r.y >> KPB_LOG);
    }
}

// ---------------------------------------------------------------------------
// Pass 4: aggregation. ONE WAVE PER NODE (both sign segs, interleaved).
// Same per-edge structure as the proven R11 kernel: wave-uniform s_load of
// e_pack, v_exp, v_fmac; per-seg edge order identical -> bit-identical h.
// Interleaving pos/neg segs (unroll 2) gives 4 independent s_load->gather
// chains per wave (2x the MLP of one-seg-per-wave). Both seg_be entries of
// a node come from one 16B scalar load. Sign-split bins: no max-subtraction
// needed (softmax shift-invariance, |w| < ~6 safe in f32).
// ---------------------------------------------------------------------------
__global__ __launch_bounds__(256) void node_agg_kernel(
        const unsigned short* __restrict__ feat16,
        const int2* __restrict__ seg_be,  // len 2N
        const uint2* __restrict__ e_pack,
        unsigned short* __restrict__ h_pos,
        unsigned short* __restrict__ h_neg, int N) {
    int lane = threadIdx.x & 63;
    int node = (blockIdx.x * blockDim.x + threadIdx.x) >> 6;
    if (node >= N) return;
    int4 be = *(const int4*)&seg_be[2 * node];  // 16B-aligned (2 int2)
    int eP   = __builtin_amdgcn_readfirstlane(be.x);
    int endP = __builtin_amdgcn_readfirstlane(be.y);
    int eN   = __builtin_amdgcn_readfirstlane(be.z);
    int endN = __builtin_amdgcn_readfirstlane(be.w);

    float sP = 0.0f, accP = 0.0f, sN = 0.0f, accN = 0.0f;

    // interleaved main loop: one pos edge + one neg edge per step (all
    // control wave-uniform; two independent dependency chains)
#pragma unroll 2
    while (eP < endP && eN < endN) {
        uint2 pkP = e_pack[eP];            // s_load
        uint2 pkN = e_pack[eN];            // s_load (independent)
        float wP = __uint_as_float(pkP.x); // >= 0
        float wN = __uint_as_float(pkN.x); // < 0
        float aP = (wP > 0.0f) ? __expf(wP) : 0.0f;  // exclude w==0
        float aN = __expf(-wN);
        sP += aP;
        sN += aN;
        accP = fmaf(bf2f(feat16[(size_t)(int)pkP.y * D + lane]), aP, accP);
        accN = fmaf(bf2f(feat16[(size_t)(int)pkN.y * D + lane]), aN, accN);
        ++eP;
        ++eN;
    }
    // tails
#pragma unroll 4
    while (eP < endP) {
        uint2 pk = e_pack[eP];
        float wj = __uint_as_float(pk.x);
        float aj = (wj > 0.0f) ? __expf(wj) : 0.0f;
        sP += aj;
        accP = fmaf(bf2f(feat16[(size_t)(int)pk.y * D + lane]), aj, accP);
        ++eP;
    }
#pragma unroll 4
    while (eN < endN) {
        uint2 pk = e_pack[eN];
        float wj = __uint_as_float(pk.x);
        float aj = __expf(-wj);
        sN += aj;
        accN = fmaf(bf2f(feat16[(size_t)(int)pk.y * D + lane]), aj, accN);
        ++eN;
    }

    h_pos[(size_t)node * D + lane] = f2bf(accP / (sP + 1e-16f));
    h_neg[(size_t)node * D + lane] = f2bf(accN / (sN + 1e-16f));
}

// ---------------------------------------------------------------------------
// Pass 5: output projection via MFMA. One wave per 16 nodes.
// A-operands are DIRECT bf16x8 loads (coef folded into Bfrag at prep).
// ---------------------------------------------------------------------------
__global__ __launch_bounds__(256) void out_gemm_mfma(
        const unsigned short* __restrict__ feat16,
        const unsigned short* __restrict__ h_pos,
        const unsigned short* __restrict__ h_neg,
        const unsigned short* __restrict__ Bfrag,
        const float* __restrict__ b_fc,
        const float* __restrict__ bias,
        float* __restrict__ out,
        int N) {
    int lane = threadIdx.x & 63;
    int wv = (blockIdx.x * blockDim.x + threadIdx.x) >> 6;
    int node0 = wv * 16;
    if (node0 >= N) return;

    const bf16x8* bp = (const bf16x8*)Bfrag;
    bf16x8 bfr[24];
#pragma unroll
    for (int f = 0; f < 24; ++f) bfr[f] = bp[f * 64 + lane];

    const unsigned short* segs[3];
    segs[0] = feat16;
    segs[1] = h_pos;
    segs[2] = h_neg;

    int m = lane & 15;          // A row / D col
    int kg = lane >> 4;         // k-group
    int node = node0 + m;
    bool mvalid = node < N;

    f32x4 acc[4];
#pragma unroll
    for (int nt = 0; nt < 4; ++nt) acc[nt] = (f32x4){0.f, 0.f, 0.f, 0.f};

#pragma unroll
    for (int kt = 0; kt < 6; ++kt) {
        int sg = kt >> 1;
        bf16x8 a;
        if (mvalid) {
            a = *(const bf16x8*)(segs[sg] + (size_t)node * D + (kt & 1) * 32 + kg * 8);
        } else {
            a = (bf16x8){0, 0, 0, 0, 0, 0, 0, 0};
        }
#pragma unroll
        for (int nt = 0; nt < 4; ++nt)
            acc[nt] = __builtin_amdgcn_mfma_f32_16x16x32_bf16(
                a, bfr[kt * 4 + nt], acc[nt], 0, 0, 0);
    }

#pragma unroll
    for (int nt = 0; nt < 4; ++nt) {
        int col = nt * 16 + m;
        float bb = b_fc[col] + bias[col];
#pragma unroll
        for (int j = 0; j < 4; ++j) {
            int row = node0 + 4 * kg + j;
            if (row < N) out[(size_t)row * OUTD + col] = acc[nt][j] + bb;
        }
    }
}

extern "C" void kernel_launch(void* const* d_in, const int* in_sizes, int n_in,
                              void* d_out, int out_size, void* d_ws, size_t ws_size,
                              hipStream_t stream) {
    const float* feat      = (const float*)d_in[0];
    const float* w         = (const float*)d_in[1];
    const float* W_fc      = (const float*)d_in[2];
    const float* b_fc      = (const float*)d_in[3];
    const float* bias      = (const float*)d_in[4];
    const float* coef_self = (const float*)d_in[5];
    const float* coef_posi = (const float*)d_in[6];
    const float* coef_nega = (const float*)d_in[7];
    const int*   src       = (const int*)d_in[8];
    const int*   dst       = (const int*)d_in[9];

    const int E = in_sizes[1];
    const int N = in_sizes[0] / D;
    const int M = 2 * N;                      // sign-split bins
    const int NB = (M + KPB - 1) / KPB;       // 196 buckets (<=256 req.)

    // Workspace layout:
    //   seg_be [M]x8B | cursorA [NB]x4 | Bfrag [12288 u16] | feat16 [N*D u16]
    //   | e_pack [NB*CAP]x8B | staged [NB*CAP]x8B | h_pos [N*D u16] | h_neg [N*D u16]
    char* ws = (char*)d_ws;
    int2*  seg_be   = (int2*)ws;
    int*   cursorA  = (int*)(ws + (size_t)M * 8);
    size_t bfrag_off = (((size_t)M * 8 + (size_t)NB * 4) + 15) & ~(size_t)15;
    unsigned short* Bfrag = (unsigned short*)(ws + bfrag_off);
    size_t feat16_off = bfrag_off + 6 * 4 * 64 * 8 * 2;
    unsigned short* feat16 = (unsigned short*)(ws + feat16_off);
    size_t epack_off = (feat16_off + (size_t)N * D * 2 + 7) & ~(size_t)7;
    uint2* e_pack  = (uint2*)(ws + epack_off);
    uint2* staged  = e_pack + (size_t)NB * CAP;
    unsigned short* h_pos = (unsigned short*)((char*)(staged + (size_t)NB * CAP));
    unsigned short* h_neg = h_pos + (size_t)N * D;

    const int ND4 = N * D / 4;
    int pb = (max(ND4, 6 * 4 * 64 * 8) + 255) / 256;
    prep_kernel<<<pb, 256, 0, stream>>>(W_fc, coef_self, coef_posi, coef_nega,
                                        feat, Bfrag, feat16, cursorA, NB, ND4);
    bin_kernel<<<(E + ABATCH - 1) / ABATCH, 256, 0, stream>>>(
        w, src, dst, cursorA, staged, E, NB);
    bucket_scatter_kernel<<<NB, 256, 0, stream>>>(cursorA, staged, seg_be,
                                                  e_pack, M);

    int nodeb = (N * 64 + 255) / 256;
    node_agg_kernel<<<nodeb, 256, 0, stream>>>(feat16, seg_be, e_pack,
                                               h_pos, h_neg, N);

    int nwaves = (N + 15) / 16;
    int gb = (nwaves + 3) / 4;  // 4 waves per 256-thread block
    out_gemm_mfma<<<gb, 256, 0, stream>>>(feat16, h_pos, h_neg, Bfrag,
                                          b_fc, bias, (float*)d_out, N);
}